// Round 12
// baseline (456.699 us; speedup 1.0000x reference)
//
#include <hip/hip_runtime.h>
#include <hip/hip_bf16.h>
#include <cstddef>

#define NNODE 20000
#define DDIM  128
#define NHEAD 4
#define NEDGE 80000
#define PSTR  1536   // unified projection row stride (1024 GAT + 512 CG)

typedef __attribute__((ext_vector_type(8))) short short8;
typedef __attribute__((ext_vector_type(4))) float f32x4;

// ---------- bf16 helpers (bit-level, RNE) ----------
__device__ __forceinline__ float bf2f(unsigned short u) {
  union { unsigned u32; float f; } c; c.u32 = ((unsigned)u) << 16; return c.f;
}
__device__ __forceinline__ unsigned short f2bf(float f) {
  union { float f; unsigned u; } c; c.f = f;
  unsigned u = c.u;
  unsigned r = 0x7FFFu + ((u >> 16) & 1u);
  return (unsigned short)((u + r) >> 16);
}

// =====================================================================
// MFMA GEMM (dual, B-in-LDS only): C[M,N] = A[M,128] @ Bt[N,128].
// A fragments read directly from global (16B/lane at the MFMA fragment
// address; L1/L2-hot). LDS = 32KB (B tile, XOR-swizzled) -> 4 blocks/CU.
// Bijective XCD-chunked block swizzle (T1/m204). A rows >= M are read
// (garbage, lands in allocated d_ws) but never stored. N % 128 == 0.
// =====================================================================
template<typename AT, typename OutT>
__global__ __launch_bounds__(256, 4) void gemm_mfma(
    const AT* __restrict__ A0, const unsigned short* __restrict__ B0, OutT* __restrict__ C0,
    const AT* __restrict__ A1, const unsigned short* __restrict__ B1, OutT* __restrict__ C1,
    int halfY, int M, int N, const float* __restrict__ bias)
{
  __shared__ unsigned short Bs[128 * 128];
  const int nwgx = gridDim.x;
  const int nwg = nwgx * gridDim.y;
  int orig = blockIdx.x + nwgx * blockIdx.y;
  int q8 = nwg >> 3, r8 = nwg & 7;
  int xc = orig & 7, lo = orig >> 3;
  int wg = ((xc < r8) ? xc * (q8 + 1) : r8 * (q8 + 1) + (xc - r8) * q8) + lo;
  int by = wg / nwgx;
  int bx = wg - by * nwgx;
  const AT* A = A0; const unsigned short* Bt = B0; OutT* C = C0;
  if (by >= halfY) { by -= halfY; A = A1; Bt = B1; C = C1; }
  const int bm = by * 128, bn = bx * 128;
  const int t = threadIdx.x;
  char* bsb = (char*)Bs;

  // ---- stage B tile (rows contiguous), XOR-swizzled LDS ----
  const char* btile = (const char*)(Bt + (size_t)bn * 128);
  #pragma unroll
  for (int i = 0; i < 8; ++i) {
    int fo = i * 4096 + t * 16;
    int r = fo >> 8, boff = fo & 255;
    short8 v = *reinterpret_cast<const short8*>(btile + fo);
    *reinterpret_cast<short8*>(bsb + r * 256 + (boff ^ ((r & 7) << 4))) = v;
  }
  __syncthreads();

  const int w = t >> 6, wr = w >> 1, wc = w & 1;
  const int lane = t & 63, l15 = lane & 15, lg = lane >> 4;
  const int rowl = bm + wr * 64 + l15;

  f32x4 acc[4][4];
  #pragma unroll
  for (int m = 0; m < 4; ++m)
    #pragma unroll
    for (int n = 0; n < 4; ++n) acc[m][n] = (f32x4){0.f, 0.f, 0.f, 0.f};

  #pragma unroll
  for (int kk = 0; kk < 4; ++kk) {
    const int kb = kk * 32 + lg * 8;
    short8 af[4], bfr[4];
    #pragma unroll
    for (int m = 0; m < 4; ++m) {
      if constexpr (sizeof(AT) == 4) {
        const float* ap = (const float*)A + ((size_t)(rowl + m * 16) << 7) + kb;
        float4 v0 = *reinterpret_cast<const float4*>(ap);
        float4 v1 = *reinterpret_cast<const float4*>(ap + 4);
        short8 hv;
        hv[0] = (short)f2bf(v0.x); hv[1] = (short)f2bf(v0.y);
        hv[2] = (short)f2bf(v0.z); hv[3] = (short)f2bf(v0.w);
        hv[4] = (short)f2bf(v1.x); hv[5] = (short)f2bf(v1.y);
        hv[6] = (short)f2bf(v1.z); hv[7] = (short)f2bf(v1.w);
        af[m] = hv;
      } else {
        af[m] = *reinterpret_cast<const short8*>(
            (const unsigned short*)A + ((size_t)(rowl + m * 16) << 7) + kb);
      }
    }
    const int kbyte = kb * 2;
    #pragma unroll
    for (int n = 0; n < 4; ++n) {
      int r = wc * 64 + n * 16 + l15;
      bfr[n] = *reinterpret_cast<const short8*>(bsb + r * 256 + (kbyte ^ ((r & 7) << 4)));
    }
    #pragma unroll
    for (int m = 0; m < 4; ++m)
      #pragma unroll
      for (int n = 0; n < 4; ++n)
        acc[m][n] = __builtin_amdgcn_mfma_f32_16x16x32_bf16(af[m], bfr[n], acc[m][n], 0, 0, 0);
  }

  // ---- epilogue: C/D map col=lane&15, row=(lane>>4)*4+reg [m89-verified] ----
  #pragma unroll
  for (int m = 0; m < 4; ++m) {
    #pragma unroll
    for (int j = 0; j < 4; ++j) {
      int row = bm + wr * 64 + m * 16 + lg * 4 + j;
      if (row >= M) continue;
      #pragma unroll
      for (int n = 0; n < 4; ++n) {
        int col = bn + wc * 64 + n * 16 + l15;
        float v = acc[m][n][j];
        if (bias) v += bias[col];
        if constexpr (sizeof(OutT) == 2) {
          C[(size_t)row * N + col] = (OutT)f2bf(v);
        } else {
          C[(size_t)row * N + col] = v;
        }
      }
    }
  }
}

// =====================================================================
// unified weight pack (one dispatch): PKU[(l,type)][1536][128] (transposed
// bf16) + PKN[l][128][128]. n<1024 = GAT cols, n>=1024 = CG cols.
// =====================================================================
__global__ __launch_bounds__(256) void pack_all(
    const float* __restrict__ gbWl, const float* __restrict__ gbWr,
    const float* __restrict__ grWl, const float* __restrict__ grWr,
    const float* __restrict__ clWf, const float* __restrict__ clWs,
    const float* __restrict__ crWf, const float* __restrict__ crWs,
    const float* __restrict__ nwW,
    unsigned short* __restrict__ PKU, unsigned short* __restrict__ PKN)
{
  int idx = blockIdx.x * 256 + threadIdx.x;
  const int NU = 2 * 2 * PSTR * 128;          // 786432
  if (idx < NU) {
    int k = idx & 127;
    int r = idx >> 7;                          // [0, 6144)
    int n = r % PSTR;
    int rt = r / PSTR;                         // [0,4)
    int type = rt & 1, l = rt >> 1;
    float v;
    if (n < 1024) {                            // GAT half
      const float* W; int col;
      if (type == 0) { if (n < 512) { W = gbWl; col = n; } else { W = grWr; col = n - 512; } }
      else           { if (n < 512) { W = gbWr; col = n; } else { W = grWl; col = n - 512; } }
      v = W[(size_t)l * 128 * 512 + (size_t)k * 512 + col];
    } else {                                   // CG half
      int nn = n - 1024, blk = nn >> 7, c = nn & 127;
      const float* W; int row;
      if (type == 0) {  // x_my: [F_lose_src | S_lose_src | F_rev_dst | S_rev_dst]
        if (blk == 0) { W = clWf; row = 128 + k; }
        else if (blk == 1) { W = clWs; row = 128 + k; }
        else if (blk == 2) { W = crWf; row = k; }
        else { W = crWs; row = k; }
      } else {          // x_opp: [F_lose_dst | S_lose_dst | F_rev_src | S_rev_src]
        if (blk == 0) { W = clWf; row = k; }
        else if (blk == 1) { W = clWs; row = k; }
        else if (blk == 2) { W = crWf; row = 128 + k; }
        else { W = crWs; row = 128 + k; }
      }
      v = W[(size_t)l * 256 * 128 + (size_t)row * 128 + c];
    }
    PKU[idx] = f2bf(v);
    return;
  }
  int i2 = idx - NU;
  if (i2 >= 2 * 128 * 128) return;
  int k = i2 & 127;
  int n = (i2 >> 7) & 127;
  int l = i2 >> 14;
  PKN[i2] = f2bf(nwW[(size_t)l * 128 * 128 + (size_t)k * 128 + n]);
}

// =====================================================================
// f32 -> bf16 convert, both inputs in one dispatch (8 elems/thread)
// =====================================================================
__global__ __launch_bounds__(256) void f2b_all(
    const float* __restrict__ inA, const float* __restrict__ inB,
    unsigned short* __restrict__ out, int nhalf)
{
  int idx = (blockIdx.x * 256 + threadIdx.x) * 8;
  if (idx >= 2 * nhalf) return;
  const float* src = (idx < nhalf) ? inA + idx : inB + (idx - nhalf);
  float4 a = *reinterpret_cast<const float4*>(src);
  float4 b = *reinterpret_cast<const float4*>(src + 4);
  short8 o;
  o[0] = (short)f2bf(a.x); o[1] = (short)f2bf(a.y);
  o[2] = (short)f2bf(a.z); o[3] = (short)f2bf(a.w);
  o[4] = (short)f2bf(b.x); o[5] = (short)f2bf(b.y);
  o[6] = (short)f2bf(b.z); o[7] = (short)f2bf(b.w);
  *reinterpret_cast<short8*>(out + idx) = o;
}

// =====================================================================
// bucket build: 4 edge sets, capacity 64 src-ids per dst (deg ~ Poisson(4))
// =====================================================================
__global__ __launch_bounds__(256) void build_buckets(
    const int* __restrict__ e0, const int* __restrict__ e1,
    const int* __restrict__ e2, const int* __restrict__ e3,
    unsigned* __restrict__ cnt, int* __restrict__ bucket)
{
  int idx = blockIdx.x * 256 + threadIdx.x;
  if (idx >= 4 * NEDGE) return;
  int set = idx / NEDGE;
  int e = idx - set * NEDGE;
  const int* ei = (set == 0) ? e0 : (set == 1) ? e1 : (set == 2) ? e2 : e3;
  int s = ei[e], d = ei[NEDGE + e];
  unsigned slot = atomicAdd(&cnt[set * NNODE + d], 1u);
  if (slot < 64u) bucket[((size_t)set * NNODE + d) * 64 + slot] = s;
}

// =====================================================================
// Fused per-dst edge kernel, 2 dsts per wave (ILP latency hiding).
// Wave owns dst d0=dbase, d1=dbase+1. All GAT gathers for BOTH dsts are
// issued before any compute (first-4 bucket indices via one int4 load);
// same for CG. Clamped duplicate indices (node 0) are valid memory and
// only predicated-used. Write (h==0 lanes): both rows of
// acc = residual + gat_bias + gat + cg.
// =====================================================================
__global__ __launch_bounds__(256) void edge_fused(
    const unsigned short* __restrict__ PJM_, const unsigned short* __restrict__ PJO_,
    const unsigned short* __restrict__ XAb_,
    const int* __restrict__ BKT_, const unsigned* __restrict__ CNT_,
    const float* __restrict__ gb_att, const float* __restrict__ gb_b,
    const float* __restrict__ cl_bf, const float* __restrict__ cl_bs,
    const float* __restrict__ gr_att, const float* __restrict__ gr_b,
    const float* __restrict__ cr_bf, const float* __restrict__ cr_bs,
    float* __restrict__ NM_, float* __restrict__ NO_, int nwb)
{
  int blk = blockIdx.x;
  int second = blk >= nwb;
  if (second) blk -= nwb;
  int dbase = blk * 8 + (int)(threadIdx.x >> 6) * 2;
  int lane = threadIdx.x & 63;
  int h = lane >> 4, q = lane & 15;

  const unsigned short *xl, *xr, *Fs, *Ss, *Fd, *Sd, *xres;
  const int *bg, *bc;
  const unsigned *cg, *cc;
  const float *att, *bias, *bf_, *bs_;
  float* acc;
  if (!second) {   // set A: dst = opp
    xl = PJM_;        xr = PJO_;
    Fs = PJM_ + 1024; Ss = PJM_ + 1152;
    Fd = PJO_ + 1024; Sd = PJO_ + 1152;
    xres = XAb_ + (size_t)NNODE * DDIM;
    bg = BKT_;                              cg = CNT_;
    bc = BKT_ + (size_t)2 * NNODE * 64;     cc = CNT_ + 2 * NNODE;
    att = gb_att; bias = gb_b; bf_ = cl_bf; bs_ = cl_bs; acc = NO_;
  } else {         // set B: dst = my
    xl = PJO_ + 512;  xr = PJM_ + 512;
    Fs = PJO_ + 1280; Ss = PJO_ + 1408;
    Fd = PJM_ + 1280; Sd = PJM_ + 1408;
    xres = XAb_;
    bg = BKT_ + (size_t)1 * NNODE * 64;     cg = CNT_ + 1 * NNODE;
    bc = BKT_ + (size_t)3 * NNODE * 64;     cc = CNT_ + 3 * NNODE;
    att = gr_att; bias = gr_b; bf_ = cr_bf; bs_ = cr_bs; acc = NM_;
  }

  const size_t off  = (size_t)h * 128 + q * 8;
  const size_t offc = (size_t)q * 8;
  const int d0 = dbase, d1 = dbase + 1;

  // ================= GAT: issue ALL loads for both dsts =================
  unsigned ng0 = cg[d0]; ng0 = (ng0 > 64u) ? 64u : ng0;
  unsigned ng1 = cg[d1]; ng1 = (ng1 > 64u) ? 64u : ng1;
  int4 gi0 = make_int4(0, 0, 0, 0), gi1 = make_int4(0, 0, 0, 0);
  if (ng0) gi0 = *reinterpret_cast<const int4*>(bg + (size_t)d0 * 64);
  if (ng1) gi1 = *reinterpret_cast<const int4*>(bg + (size_t)d1 * 64);
  int s00 = (ng0 > 0u) ? gi0.x : 0, s01 = (ng0 > 1u) ? gi0.y : 0;
  int s02 = (ng0 > 2u) ? gi0.z : 0, s03 = (ng0 > 3u) ? gi0.w : 0;
  int s10 = (ng1 > 0u) ? gi1.x : 0, s11 = (ng1 > 1u) ? gi1.y : 0;
  int s12 = (ng1 > 2u) ? gi1.z : 0, s13 = (ng1 > 3u) ? gi1.w : 0;

  short8 xrv0 = *reinterpret_cast<const short8*>(xr + (size_t)d0 * PSTR + off);
  short8 xrv1 = *reinterpret_cast<const short8*>(xr + (size_t)d1 * PSTR + off);
  short8 a00 = *reinterpret_cast<const short8*>(xl + (size_t)s00 * PSTR + off);
  short8 a01 = *reinterpret_cast<const short8*>(xl + (size_t)s01 * PSTR + off);
  short8 a02 = *reinterpret_cast<const short8*>(xl + (size_t)s02 * PSTR + off);
  short8 a03 = *reinterpret_cast<const short8*>(xl + (size_t)s03 * PSTR + off);
  short8 a10 = *reinterpret_cast<const short8*>(xl + (size_t)s10 * PSTR + off);
  short8 a11 = *reinterpret_cast<const short8*>(xl + (size_t)s11 * PSTR + off);
  short8 a12 = *reinterpret_cast<const short8*>(xl + (size_t)s12 * PSTR + off);
  short8 a13 = *reinterpret_cast<const short8*>(xl + (size_t)s13 * PSTR + off);

  float4 at0 = *reinterpret_cast<const float4*>(att + h * 128 + q * 8);
  float4 at1 = *reinterpret_cast<const float4*>(att + h * 128 + q * 8 + 4);
  float atf[8] = { at0.x, at0.y, at0.z, at0.w, at1.x, at1.y, at1.z, at1.w };
  float xrf0[8], xrf1[8];
  #pragma unroll
  for (int j = 0; j < 8; ++j) { xrf0[j] = bf2f((unsigned short)xrv0[j]);
                                xrf1[j] = bf2f((unsigned short)xrv1[j]); }

  float uo0[8] = {0,0,0,0,0,0,0,0}, uo1[8] = {0,0,0,0,0,0,0,0};
  float ss0 = 0.f, ss1 = 0.f;

#define GATP(XLV, XRF, UO, SSUM) { \
    float xlf[8]; \
    _Pragma("unroll") for (int j = 0; j < 8; ++j) xlf[j] = bf2f((unsigned short)(XLV)[j]); \
    float sum = 0.f; \
    _Pragma("unroll") for (int j = 0; j < 8; ++j) { \
      float z = xlf[j] + XRF[j]; \
      z = (z > 0.f) ? z : 0.2f * z; \
      sum += atf[j] * z; } \
    _Pragma("unroll") for (int m = 1; m < 16; m <<= 1) sum += __shfl_xor(sum, m); \
    float e = __expf(fminf(sum, 80.f)); \
    SSUM += e; \
    _Pragma("unroll") for (int j = 0; j < 8; ++j) UO[j] += e * xlf[j]; }

  if (ng0 > 0u) GATP(a00, xrf0, uo0, ss0);
  if (ng1 > 0u) GATP(a10, xrf1, uo1, ss1);
  if (ng0 > 1u) GATP(a01, xrf0, uo0, ss0);
  if (ng1 > 1u) GATP(a11, xrf1, uo1, ss1);
  if (ng0 > 2u) GATP(a02, xrf0, uo0, ss0);
  if (ng1 > 2u) GATP(a12, xrf1, uo1, ss1);
  if (ng0 > 3u) GATP(a03, xrf0, uo0, ss0);
  if (ng1 > 3u) GATP(a13, xrf1, uo1, ss1);
  for (unsigned i = 4; i < ng0; ++i) {          // rare tail (deg > 4)
    int s = bg[(size_t)d0 * 64 + i];
    short8 xv = *reinterpret_cast<const short8*>(xl + (size_t)s * PSTR + off);
    GATP(xv, xrf0, uo0, ss0);
  }
  for (unsigned i = 4; i < ng1; ++i) {
    int s = bg[(size_t)d1 * 64 + i];
    short8 xv = *reinterpret_cast<const short8*>(xl + (size_t)s * PSTR + off);
    GATP(xv, xrf1, uo1, ss1);
  }
  float sc0 = __builtin_amdgcn_rcpf(ss0 + 1e-16f) * 0.25f;   // /denom, /H
  float sc1 = __builtin_amdgcn_rcpf(ss1 + 1e-16f) * 0.25f;
  #pragma unroll
  for (int j = 0; j < 8; ++j) {
    float v0 = uo0[j] * sc0, v1 = uo1[j] * sc1;
    v0 += __shfl_xor(v0, 16); v1 += __shfl_xor(v1, 16);      // sum over heads
    v0 += __shfl_xor(v0, 32); v1 += __shfl_xor(v1, 32);
    uo0[j] = v0; uo1[j] = v1;
  }

  // ================= CG: issue ALL loads for both dsts =================
  unsigned nc0 = cc[d0]; nc0 = (nc0 > 64u) ? 64u : nc0;
  unsigned nc1 = cc[d1]; nc1 = (nc1 > 64u) ? 64u : nc1;
  unsigned ia = (unsigned)h, ib = (unsigned)h + 4u;
  bool p0a = ia < nc0, p0b = ib < nc0, p1a = ia < nc1, p1b = ib < nc1;
  int c0a = p0a ? bc[(size_t)d0 * 64 + ia] : 0;
  int c0b = p0b ? bc[(size_t)d0 * 64 + ib] : 0;
  int c1a = p1a ? bc[(size_t)d1 * 64 + ia] : 0;
  int c1b = p1b ? bc[(size_t)d1 * 64 + ib] : 0;

  short8 fd0v = *reinterpret_cast<const short8*>(Fd + (size_t)d0 * PSTR + offc);
  short8 sd0v = *reinterpret_cast<const short8*>(Sd + (size_t)d0 * PSTR + offc);
  short8 fd1v = *reinterpret_cast<const short8*>(Fd + (size_t)d1 * PSTR + offc);
  short8 sd1v = *reinterpret_cast<const short8*>(Sd + (size_t)d1 * PSTR + offc);
  short8 f0a = *reinterpret_cast<const short8*>(Fs + (size_t)c0a * PSTR + offc);
  short8 s0a = *reinterpret_cast<const short8*>(Ss + (size_t)c0a * PSTR + offc);
  short8 f0b = *reinterpret_cast<const short8*>(Fs + (size_t)c0b * PSTR + offc);
  short8 s0b = *reinterpret_cast<const short8*>(Ss + (size_t)c0b * PSTR + offc);
  short8 f1a = *reinterpret_cast<const short8*>(Fs + (size_t)c1a * PSTR + offc);
  short8 s1a = *reinterpret_cast<const short8*>(Ss + (size_t)c1a * PSTR + offc);
  short8 f1b = *reinterpret_cast<const short8*>(Fs + (size_t)c1b * PSTR + offc);
  short8 s1b = *reinterpret_cast<const short8*>(Ss + (size_t)c1b * PSTR + offc);

  float fd0[8], sd0[8], fd1[8], sd1[8], ac0[8], ac1[8];
  {
    const float* bfp = bf_ + q * 8;
    const float* bsp = bs_ + q * 8;
    #pragma unroll
    for (int j = 0; j < 8; ++j) {
      fd0[j] = bf2f((unsigned short)fd0v[j]) + bfp[j];
      sd0[j] = bf2f((unsigned short)sd0v[j]) + bsp[j];
      fd1[j] = bf2f((unsigned short)fd1v[j]) + bfp[j];
      sd1[j] = bf2f((unsigned short)sd1v[j]) + bsp[j];
      ac0[j] = 0.f; ac1[j] = 0.f;
    }
  }

#define CGP(FV, SV, FD, SD, AC) { \
    _Pragma("unroll") for (int j = 0; j < 8; ++j) { \
      float g  = FD[j] + bf2f((unsigned short)(FV)[j]); \
      float tt = SD[j] + bf2f((unsigned short)(SV)[j]); \
      float gate = __builtin_amdgcn_rcpf(1.f + __expf(-g)); \
      float sp = fmaxf(tt, 0.f) + __logf(1.f + __expf(-fabsf(tt))); \
      AC[j] += gate * sp; } }

  if (p0a) CGP(f0a, s0a, fd0, sd0, ac0);
  if (p1a) CGP(f1a, s1a, fd1, sd1, ac1);
  if (p0b) CGP(f0b, s0b, fd0, sd0, ac0);
  if (p1b) CGP(f1b, s1b, fd1, sd1, ac1);
  for (unsigned i = (unsigned)h + 8u; i < nc0; i += 4u) {    // rare (deg > 8)
    int s = bc[(size_t)d0 * 64 + i];
    short8 fv = *reinterpret_cast<const short8*>(Fs + (size_t)s * PSTR + offc);
    short8 sv = *reinterpret_cast<const short8*>(Ss + (size_t)s * PSTR + offc);
    CGP(fv, sv, fd0, sd0, ac0);
  }
  for (unsigned i = (unsigned)h + 8u; i < nc1; i += 4u) {
    int s = bc[(size_t)d1 * 64 + i];
    short8 fv = *reinterpret_cast<const short8*>(Fs + (size_t)s * PSTR + offc);
    short8 sv = *reinterpret_cast<const short8*>(Ss + (size_t)s * PSTR + offc);
    CGP(fv, sv, fd1, sd1, ac1);
  }
  #pragma unroll
  for (int j = 0; j < 8; ++j) {
    float v0 = ac0[j], v1 = ac1[j];
    v0 += __shfl_xor(v0, 16); v1 += __shfl_xor(v1, 16);      // sum over 4 groups
    v0 += __shfl_xor(v0, 32); v1 += __shfl_xor(v1, 32);
    ac0[j] = v0; ac1[j] = v1;
  }

  // ================= combine & write (lanes h==0), both dsts ===========
  if (h == 0) {
    short8 xs0 = *reinterpret_cast<const short8*>(xres + (size_t)d0 * 128 + q * 8);
    short8 xs1 = *reinterpret_cast<const short8*>(xres + (size_t)d1 * 128 + q * 8);
    const float* bp = bias + q * 8;
    float4 o0, o1;
    o0.x = uo0[0] + ac0[0] + bf2f((unsigned short)xs0[0]) + bp[0];
    o0.y = uo0[1] + ac0[1] + bf2f((unsigned short)xs0[1]) + bp[1];
    o0.z = uo0[2] + ac0[2] + bf2f((unsigned short)xs0[2]) + bp[2];
    o0.w = uo0[3] + ac0[3] + bf2f((unsigned short)xs0[3]) + bp[3];
    o1.x = uo0[4] + ac0[4] + bf2f((unsigned short)xs0[4]) + bp[4];
    o1.y = uo0[5] + ac0[5] + bf2f((unsigned short)xs0[5]) + bp[5];
    o1.z = uo0[6] + ac0[6] + bf2f((unsigned short)xs0[6]) + bp[6];
    o1.w = uo0[7] + ac0[7] + bf2f((unsigned short)xs0[7]) + bp[7];
    *reinterpret_cast<float4*>(acc + (size_t)d0 * 128 + q * 8) = o0;
    *reinterpret_cast<float4*>(acc + (size_t)d0 * 128 + q * 8 + 4) = o1;
    o0.x = uo1[0] + ac1[0] + bf2f((unsigned short)xs1[0]) + bp[0];
    o0.y = uo1[1] + ac1[1] + bf2f((unsigned short)xs1[1]) + bp[1];
    o0.z = uo1[2] + ac1[2] + bf2f((unsigned short)xs1[2]) + bp[2];
    o0.w = uo1[3] + ac1[3] + bf2f((unsigned short)xs1[3]) + bp[3];
    o1.x = uo1[4] + ac1[4] + bf2f((unsigned short)xs1[4]) + bp[4];
    o1.y = uo1[5] + ac1[5] + bf2f((unsigned short)xs1[5]) + bp[5];
    o1.z = uo1[6] + ac1[6] + bf2f((unsigned short)xs1[6]) + bp[6];
    o1.w = uo1[7] + ac1[7] + bf2f((unsigned short)xs1[7]) + bp[7];
    *reinterpret_cast<float4*>(acc + (size_t)d1 * 128 + q * 8) = o0;
    *reinterpret_cast<float4*>(acc + (size_t)d1 * 128 + q * 8 + 4) = o1;
  }
}

// =====================================================================

extern "C" void kernel_launch(void* const* d_in, const int* in_sizes, int n_in,
                              void* d_out, int out_size, void* d_ws, size_t ws_size,
                              hipStream_t stream) {
  const float* x_my_in  = (const float*)d_in[0];
  const float* x_opp_in = (const float*)d_in[1];
  const float* gb_Wl  = (const float*)d_in[2];
  const float* gb_Wr  = (const float*)d_in[3];
  const float* gb_att = (const float*)d_in[4];
  const float* gb_b   = (const float*)d_in[5];
  const float* gr_Wl  = (const float*)d_in[6];
  const float* gr_Wr  = (const float*)d_in[7];
  const float* gr_att = (const float*)d_in[8];
  const float* gr_b   = (const float*)d_in[9];
  const float* cl_Wf  = (const float*)d_in[10];
  const float* cl_bf  = (const float*)d_in[11];
  const float* cl_Ws  = (const float*)d_in[12];
  const float* cl_bs  = (const float*)d_in[13];
  const float* cr_Wf  = (const float*)d_in[14];
  const float* cr_bf  = (const float*)d_in[15];
  const float* cr_Ws  = (const float*)d_in[16];
  const float* cr_bs  = (const float*)d_in[17];
  const float* nw_W   = (const float*)d_in[18];
  const float* nw_b   = (const float*)d_in[19];
  const int* ei_beats     = (const int*)d_in[20];
  const int* ei_loses     = (const int*)d_in[21];
  const int* ei_rev_beats = (const int*)d_in[22];
  const int* ei_rev_loses = (const int*)d_in[23];

  float* out = (float*)d_out;

  const size_t ND = (size_t)NNODE * DDIM;        // 2,560,000
  unsigned short* XAb = (unsigned short*)d_ws;    // [x_my ; x_opp] bf16 (10.2MB)
  float* NM  = (float*)(XAb + 2 * ND);            // [NM ; NO] f32 (20.5MB)
  float* NO  = NM + ND;
  unsigned short* PJM = (unsigned short*)(NM + 2 * ND);      // unified proj my  (61.4MB)
  unsigned short* PJO = PJM + (size_t)NNODE * PSTR;          // unified proj opp (61.4MB)
  unsigned* CNT = (unsigned*)(PJO + (size_t)NNODE * PSTR);   // 4 x 20000
  int* BKT = (int*)(CNT + 4 * NNODE);                        // 4 x 20000 x 64 (20.5MB)
  unsigned short* PKU = (unsigned short*)(BKT + (size_t)4 * NNODE * 64);  // 1.57MB
  unsigned short* PKN = PKU + 2 * 2 * PSTR * 128;                         // 64KB

  const int nwb = NNODE / 8;                      // 2500 blocks per node type

  // ---- pack all weights (one dispatch) ----
  hipLaunchKernelGGL(pack_all, dim3((2 * 2 * PSTR * 128 + 2 * 128 * 128) / 256), dim3(256),
                     0, stream, gb_Wl, gb_Wr, gr_Wl, gr_Wr,
                     cl_Wf, cl_Ws, cr_Wf, cr_Ws, nw_W, PKU, PKN);

  // ---- convert both inputs to bf16 (one dispatch) ----
  hipLaunchKernelGGL(f2b_all, dim3((int)(2 * ND / 8 / 256)), dim3(256), 0, stream,
                     x_my_in, x_opp_in, XAb, (int)ND);

  // ---- build dst buckets once (edge sets are layer-invariant) ----
  // set 0 = gat beats (dst=opp), 1 = gat rev_loses (dst=my),
  // set 2 = cg loses  (dst=opp), 3 = cg rev_beats  (dst=my)
  hipMemsetAsync(CNT, 0, 4 * NNODE * sizeof(unsigned), stream);
  hipLaunchKernelGGL(build_buckets, dim3((4 * NEDGE + 255) / 256), dim3(256), 0, stream,
                     ei_beats, ei_rev_loses, ei_loses, ei_rev_beats, CNT, BKT);

  for (int l = 0; l < 2; ++l) {
    const size_t oA = (size_t)l * NHEAD * DDIM;
    const size_t oB = (size_t)l * DDIM;

    // ---- unified projections (dual, N=1536):
    // PJM = [my@gbWl | my@grWr | Fls | Sls | Frd | Srd]
    // PJO = [opp@gbWr | opp@grWl | Fld | Sld | Frs | Srs]
    hipLaunchKernelGGL((gemm_mfma<unsigned short, unsigned short>), dim3(12, 314), dim3(256), 0, stream,
                       XAb,      PKU + (size_t)(l * 2 + 0) * PSTR * 128, PJM,
                       XAb + ND, PKU + (size_t)(l * 2 + 1) * PSTR * 128, PJO,
                       157, NNODE, PSTR, (const float*)nullptr);

    // ---- fused edge kernel: set A (dst=opp -> NO), set B (dst=my -> NM)
    hipLaunchKernelGGL(edge_fused, dim3(2 * nwb), dim3(256), 0, stream,
                       PJM, PJO, XAb, BKT, CNT,
                       gb_att + oA, gb_b + oB, cl_bf + oB, cl_bs + oB,
                       gr_att + oA, gr_b + oB, cr_bf + oB, cr_bs + oB,
                       NM, NO, nwb);

    // ---- shared nodewise Linear over [NM ; NO] (f32 A, converted in fragments)
    if (l == 0) {
      hipLaunchKernelGGL((gemm_mfma<float, unsigned short>), dim3(1, 313), dim3(256), 0, stream,
                         NM, PKN + (size_t)l * 128 * 128, XAb,
                         NM, PKN + (size_t)l * 128 * 128, XAb,
                         313, 2 * NNODE, 128, nw_b + oB);
    } else {
      hipLaunchKernelGGL((gemm_mfma<float, float>), dim3(1, 313), dim3(256), 0, stream,
                         NM, PKN + (size_t)l * 128 * 128, out,
                         NM, PKN + (size_t)l * 128 * 128, out,
                         313, 2 * NNODE, 128, nw_b + oB);
    }
  }
  (void)in_sizes; (void)n_in; (void)out_size; (void)ws_size;
}